// Round 1
// baseline (2841.929 us; speedup 1.0000x reference)
//
#include <hip/hip_runtime.h>
#include <hip/hip_bf16.h>

// GCN VGAE encoder, fp32 throughout.
// Structure: deg/dinv -> norm -> t1=x@W1 -> agg1=selfloop+b1 (+ edge scatter)
//            -> t2=relu(agg1)@[Wmu|Wls] -> out=selfloop+b (+ edge scatter, split mu/ls)
// Aggregation is atomic scatter (unsafeAtomicAdd -> global_atomic_add_f32).

constexpr int BLK = 256;

__device__ __forceinline__ void fma4(float4& a, float s, const float4& w) {
    a.x = fmaf(s, w.x, a.x);
    a.y = fmaf(s, w.y, a.y);
    a.z = fmaf(s, w.z, a.z);
    a.w = fmaf(s, w.w, a.w);
}

__global__ void k_count_deg(const int* __restrict__ col, int E, float* __restrict__ deg) {
    int i = blockIdx.x * BLK + threadIdx.x;
    if (i < E) unsafeAtomicAdd(&deg[col[i]], 1.0f);
}

// in-place: deg -> dinv = rsqrt(deg+1)
__global__ void k_dinv(float* __restrict__ deg, int N) {
    int i = blockIdx.x * BLK + threadIdx.x;
    if (i < N) deg[i] = rsqrtf(deg[i] + 1.0f);
}

__global__ void k_norm(const int* __restrict__ row, const int* __restrict__ col,
                       const float* __restrict__ dinv, float* __restrict__ norm, int E) {
    int i = blockIdx.x * BLK + threadIdx.x;
    if (i < E) norm[i] = dinv[row[i]] * dinv[col[i]];
}

// T[N,64] = op(X[N,K]) @ W   (W = Wa[K,64], or [Wa|Wb] with Wa,Wb [K,32] when TWO_W)
// 256 threads: fg = tid&15 (float4 output group), ns = tid>>4; 32 nodes/block (2/thread).
template <int K, bool RELU, bool TWO_W>
__global__ __launch_bounds__(256) void k_gemm(const float* __restrict__ X,
                                              const float* __restrict__ Wa,
                                              const float* __restrict__ Wb,
                                              float* __restrict__ T, int N) {
    __shared__ float4 Wl[K * 16];
    const int tid = threadIdx.x;
    for (int i = tid; i < K * 16; i += 256) {
        if (TWO_W) {
            int k = i >> 4, fg = i & 15;
            const float* s = (fg < 8) ? (Wa + k * 32 + fg * 4)
                                      : (Wb + k * 32 + (fg - 8) * 4);
            Wl[i] = *reinterpret_cast<const float4*>(s);
        } else {
            Wl[i] = reinterpret_cast<const float4*>(Wa)[i];
        }
    }
    __syncthreads();

    const int fg = tid & 15;
    const int ns = tid >> 4;
    const int n0 = blockIdx.x * 32 + ns;
    const int n1 = n0 + 16;
    const bool v0 = n0 < N, v1 = n1 < N;
    const float4* Xv = reinterpret_cast<const float4*>(X);
    const float4 z = make_float4(0.f, 0.f, 0.f, 0.f);
    float4 a0 = z, a1 = z;

    for (int k4 = 0; k4 < K / 4; ++k4) {
        float4 x0 = v0 ? Xv[n0 * (K / 4) + k4] : z;
        float4 x1 = v1 ? Xv[n1 * (K / 4) + k4] : z;
        if (RELU) {
            x0.x = fmaxf(x0.x, 0.f); x0.y = fmaxf(x0.y, 0.f);
            x0.z = fmaxf(x0.z, 0.f); x0.w = fmaxf(x0.w, 0.f);
            x1.x = fmaxf(x1.x, 0.f); x1.y = fmaxf(x1.y, 0.f);
            x1.z = fmaxf(x1.z, 0.f); x1.w = fmaxf(x1.w, 0.f);
        }
        float4 w0 = Wl[(k4 * 4 + 0) * 16 + fg];
        float4 w1 = Wl[(k4 * 4 + 1) * 16 + fg];
        float4 w2 = Wl[(k4 * 4 + 2) * 16 + fg];
        float4 w3 = Wl[(k4 * 4 + 3) * 16 + fg];
        fma4(a0, x0.x, w0); fma4(a0, x0.y, w1); fma4(a0, x0.z, w2); fma4(a0, x0.w, w3);
        fma4(a1, x1.x, w0); fma4(a1, x1.y, w1); fma4(a1, x1.z, w2); fma4(a1, x1.w, w3);
    }
    if (v0) reinterpret_cast<float4*>(T)[n0 * 16 + fg] = a0;
    if (v1) reinterpret_cast<float4*>(T)[n1 * 16 + fg] = a1;
}

// agg[n][f] = T[n][f]*dinv[n]^2 + bias[f]   (64 feats; also zero-initializes agg)
__global__ void k_selfinit(const float* __restrict__ T, const float* __restrict__ dinv,
                           const float* __restrict__ bias, float* __restrict__ agg, int N) {
    int g = blockIdx.x * BLK + threadIdx.x;
    int n = g >> 4, fg = g & 15;
    if (n >= N) return;
    float d = dinv[n];
    float d2 = d * d;
    float4 t = reinterpret_cast<const float4*>(T)[g];
    float4 b = reinterpret_cast<const float4*>(bias)[fg];
    float4 o;
    o.x = fmaf(t.x, d2, b.x); o.y = fmaf(t.y, d2, b.y);
    o.z = fmaf(t.z, d2, b.z); o.w = fmaf(t.w, d2, b.w);
    reinterpret_cast<float4*>(agg)[g] = o;
}

// out layout: mu [N,32] then logstd [N,32]. T2[n][0:32]->mu, [32:64]->logstd.
__global__ void k_selfinit_out(const float* __restrict__ T2, const float* __restrict__ dinv,
                               const float* __restrict__ bmu, const float* __restrict__ bls,
                               float* __restrict__ out, int N) {
    int g = blockIdx.x * BLK + threadIdx.x;
    int n = g >> 4, fg = g & 15;
    if (n >= N) return;
    float d = dinv[n];
    float d2 = d * d;
    float4 t = reinterpret_cast<const float4*>(T2)[g];
    float4 b;
    float4* dst;
    if (fg < 8) {
        b = reinterpret_cast<const float4*>(bmu)[fg];
        dst = reinterpret_cast<float4*>(out) + (size_t)n * 8 + fg;
    } else {
        b = reinterpret_cast<const float4*>(bls)[fg - 8];
        dst = reinterpret_cast<float4*>(out + (size_t)N * 32) + (size_t)n * 8 + (fg - 8);
    }
    float4 o;
    o.x = fmaf(t.x, d2, b.x); o.y = fmaf(t.y, d2, b.y);
    o.z = fmaf(t.z, d2, b.z); o.w = fmaf(t.w, d2, b.w);
    *dst = o;
}

// 16 threads/edge, float4 each: agg[col] += T[row]*norm. SPLIT routes mu/ls halves of d_out.
template <bool SPLIT>
__global__ void k_scatter(const int* __restrict__ row, const int* __restrict__ col,
                          const float* __restrict__ norm, const float* __restrict__ T,
                          float* __restrict__ out, int E, int N) {
    int g = blockIdx.x * BLK + threadIdx.x;
    int e = g >> 4, fg = g & 15;
    if (e >= E) return;
    int r = row[e], c = col[e];
    float nm = norm[e];
    float4 v = reinterpret_cast<const float4*>(T)[r * 16 + fg];
    float* dst;
    if (SPLIT) {
        dst = (fg < 8) ? (out + (size_t)c * 32 + fg * 4)
                       : (out + (size_t)N * 32 + (size_t)c * 32 + (fg - 8) * 4);
    } else {
        dst = out + (size_t)c * 64 + fg * 4;
    }
    unsafeAtomicAdd(dst + 0, v.x * nm);
    unsafeAtomicAdd(dst + 1, v.y * nm);
    unsafeAtomicAdd(dst + 2, v.z * nm);
    unsafeAtomicAdd(dst + 3, v.w * nm);
}

extern "C" void kernel_launch(void* const* d_in, const int* in_sizes, int n_in,
                              void* d_out, int out_size, void* d_ws, size_t ws_size,
                              hipStream_t stream) {
    const float* x   = (const float*)d_in[0];
    const int*   ei  = (const int*)d_in[1];
    const float* W1  = (const float*)d_in[2];
    const float* b1  = (const float*)d_in[3];
    const float* Wmu = (const float*)d_in[4];
    const float* bmu = (const float*)d_in[5];
    const float* Wls = (const float*)d_in[6];
    const float* bls = (const float*)d_in[7];

    const int N = in_sizes[0] / 128;
    const int E = in_sizes[1] / 2;
    const int* row = ei;       // sources
    const int* col = ei + E;   // targets

    float* ws   = (float*)d_ws;
    float* dinv = ws;                         // N floats (deg, then dinv in-place)
    float* norm = dinv + N;                   // E floats
    float* t1   = norm + E;                   // 64N floats
    float* agg1 = t1 + (size_t)64 * N;        // 64N floats
    float* t2   = t1;                         // reuse t1 (dead after scatter1)
    float* outp = (float*)d_out;

    hipMemsetAsync(dinv, 0, (size_t)N * sizeof(float), stream);
    k_count_deg<<<(E + BLK - 1) / BLK, BLK, 0, stream>>>(col, E, dinv);
    k_dinv<<<(N + BLK - 1) / BLK, BLK, 0, stream>>>(dinv, N);
    k_norm<<<(E + BLK - 1) / BLK, BLK, 0, stream>>>(row, col, dinv, norm, E);

    k_gemm<128, false, false><<<(N + 31) / 32, 256, 0, stream>>>(x, W1, nullptr, t1, N);
    k_selfinit<<<(N * 16 + BLK - 1) / BLK, BLK, 0, stream>>>(t1, dinv, b1, agg1, N);
    k_scatter<false><<<(int)(((size_t)E * 16 + BLK - 1) / BLK), BLK, 0, stream>>>(
        row, col, norm, t1, agg1, E, N);

    k_gemm<64, true, true><<<(N + 31) / 32, 256, 0, stream>>>(agg1, Wmu, Wls, t2, N);
    k_selfinit_out<<<(N * 16 + BLK - 1) / BLK, BLK, 0, stream>>>(t2, dinv, bmu, bls, outp, N);
    k_scatter<true><<<(int)(((size_t)E * 16 + BLK - 1) / BLK), BLK, 0, stream>>>(
        row, col, norm, t2, outp, E, N);
}

// Round 2
// 525.092 us; speedup vs baseline: 5.4123x; 5.4123x over previous
//
#include <hip/hip_runtime.h>
#include <hip/hip_bf16.h>

// GCN VGAE encoder, fp32, atomic-free aggregation via CSR gather.
// norm factorization: agg[c] = dinv[c]*(sum_e ts[src] + ts[c]) + b, ts = (X@W)*dinv.

constexpr int BLK = 256;

__device__ __forceinline__ void fma4(float4& a, float s, const float4& w) {
    a.x = fmaf(s, w.x, a.x);
    a.y = fmaf(s, w.y, a.y);
    a.z = fmaf(s, w.z, a.z);
    a.w = fmaf(s, w.w, a.w);
}

__global__ void k_count_deg(const int* __restrict__ col, int E, int* __restrict__ deg) {
    int i = blockIdx.x * BLK + threadIdx.x;
    if (i < E) atomicAdd(&deg[col[i]], 1);
}

__global__ void k_dinv(const int* __restrict__ deg, float* __restrict__ dinv, int N) {
    int i = blockIdx.x * BLK + threadIdx.x;
    if (i < N) dinv[i] = rsqrtf((float)deg[i] + 1.0f);
}

// Single-block exclusive scan of deg[N] -> cursor[N]. ~49 chunks of 1024.
__global__ __launch_bounds__(1024) void k_scan(const int* __restrict__ deg,
                                               int* __restrict__ cursor, int N) {
    __shared__ int wsum[16];
    __shared__ int carry_s;
    const int tid = threadIdx.x;
    const int lane = tid & 63, wid = tid >> 6;
    if (tid == 0) carry_s = 0;
    __syncthreads();
    for (int base = 0; base < N; base += 1024) {
        int i = base + tid;
        int v = (i < N) ? deg[i] : 0;
        int s = v;
        #pragma unroll
        for (int off = 1; off < 64; off <<= 1) {
            int u = __shfl_up(s, off, 64);
            if (lane >= off) s += u;
        }
        if (lane == 63) wsum[wid] = s;
        __syncthreads();
        if (tid < 16) {
            int ws = wsum[tid];
            #pragma unroll
            for (int off = 1; off < 16; off <<= 1) {
                int u = __shfl_up(ws, off, 16);
                if (tid >= off) ws += u;
            }
            wsum[tid] = ws;
        }
        __syncthreads();
        int carry = carry_s;
        int excl = carry + (wid > 0 ? wsum[wid - 1] : 0) + s - v;
        if (i < N) cursor[i] = excl;
        int total = wsum[15];
        __syncthreads();
        if (tid == 0) carry_s = carry + total;
        __syncthreads();
    }
}

// Fill srcidx bucketed by col. Afterwards cursor[i] == rowptr[i+1].
__global__ void k_bucket(const int* __restrict__ row, const int* __restrict__ col,
                         int* __restrict__ cursor, int* __restrict__ srcidx, int E) {
    int i = blockIdx.x * BLK + threadIdx.x;
    if (i < E) {
        int c = col[i];
        int pos = atomicAdd(&cursor[c], 1);
        srcidx[pos] = row[i];
    }
}

// T[N,64] = (op(X[N,K]) @ W) * dinv[n]   (W = Wa[K,64] or [Wa|Wb], Wa,Wb [K,32])
template <int K, bool RELU, bool TWO_W>
__global__ __launch_bounds__(256) void k_gemm(const float* __restrict__ X,
                                              const float* __restrict__ Wa,
                                              const float* __restrict__ Wb,
                                              const float* __restrict__ dinv,
                                              float* __restrict__ T, int N) {
    __shared__ float4 Wl[K * 16];
    const int tid = threadIdx.x;
    for (int i = tid; i < K * 16; i += 256) {
        if (TWO_W) {
            int k = i >> 4, fg = i & 15;
            const float* s = (fg < 8) ? (Wa + k * 32 + fg * 4)
                                      : (Wb + k * 32 + (fg - 8) * 4);
            Wl[i] = *reinterpret_cast<const float4*>(s);
        } else {
            Wl[i] = reinterpret_cast<const float4*>(Wa)[i];
        }
    }
    __syncthreads();

    const int fg = tid & 15;
    const int ns = tid >> 4;
    const int n0 = blockIdx.x * 32 + ns;
    const int n1 = n0 + 16;
    const bool v0 = n0 < N, v1 = n1 < N;
    const float4* Xv = reinterpret_cast<const float4*>(X);
    const float4 z = make_float4(0.f, 0.f, 0.f, 0.f);
    float4 a0 = z, a1 = z;

    for (int k4 = 0; k4 < K / 4; ++k4) {
        float4 x0 = v0 ? Xv[n0 * (K / 4) + k4] : z;
        float4 x1 = v1 ? Xv[n1 * (K / 4) + k4] : z;
        if (RELU) {
            x0.x = fmaxf(x0.x, 0.f); x0.y = fmaxf(x0.y, 0.f);
            x0.z = fmaxf(x0.z, 0.f); x0.w = fmaxf(x0.w, 0.f);
            x1.x = fmaxf(x1.x, 0.f); x1.y = fmaxf(x1.y, 0.f);
            x1.z = fmaxf(x1.z, 0.f); x1.w = fmaxf(x1.w, 0.f);
        }
        float4 w0 = Wl[(k4 * 4 + 0) * 16 + fg];
        float4 w1 = Wl[(k4 * 4 + 1) * 16 + fg];
        float4 w2 = Wl[(k4 * 4 + 2) * 16 + fg];
        float4 w3 = Wl[(k4 * 4 + 3) * 16 + fg];
        fma4(a0, x0.x, w0); fma4(a0, x0.y, w1); fma4(a0, x0.z, w2); fma4(a0, x0.w, w3);
        fma4(a1, x1.x, w0); fma4(a1, x1.y, w1); fma4(a1, x1.z, w2); fma4(a1, x1.w, w3);
    }
    if (v0) {
        float d = dinv[n0];
        a0.x *= d; a0.y *= d; a0.z *= d; a0.w *= d;
        reinterpret_cast<float4*>(T)[n0 * 16 + fg] = a0;
    }
    if (v1) {
        float d = dinv[n1];
        a1.x *= d; a1.y *= d; a1.z *= d; a1.w *= d;
        reinterpret_cast<float4*>(T)[n1 * 16 + fg] = a1;
    }
}

// out[n] = dinv[n]*(sum_{k in [cur[n-1],cur[n])} Ts[srcidx[k]] + Ts[n]) + bias
// 16 threads/node, float4 each. SPLIT routes feats 0:32 -> out, 32:64 -> out+32N.
template <bool SPLIT>
__global__ __launch_bounds__(256) void k_gather(const int* __restrict__ cursor,
                                                const int* __restrict__ srcidx,
                                                const float* __restrict__ Ts,
                                                const float* __restrict__ dinv,
                                                const float* __restrict__ ba,
                                                const float* __restrict__ bb,
                                                float* __restrict__ out, int N) {
    int g = blockIdx.x * BLK + threadIdx.x;
    int n = g >> 4, fg = g & 15;
    if (n >= N) return;
    int start = (n == 0) ? 0 : cursor[n - 1];
    int end = cursor[n];
    const float4* Tv = reinterpret_cast<const float4*>(Ts);
    // self loop: + ts[n]
    float4 acc = Tv[n * 16 + fg];
    int k = start;
    for (; k + 1 < end; k += 2) {
        int r0 = srcidx[k], r1 = srcidx[k + 1];
        float4 v0 = Tv[r0 * 16 + fg];
        float4 v1 = Tv[r1 * 16 + fg];
        acc.x += v0.x + v1.x; acc.y += v0.y + v1.y;
        acc.z += v0.z + v1.z; acc.w += v0.w + v1.w;
    }
    if (k < end) {
        float4 v0 = Tv[srcidx[k] * 16 + fg];
        acc.x += v0.x; acc.y += v0.y; acc.z += v0.z; acc.w += v0.w;
    }
    float d = dinv[n];
    float4 b;
    float4* dst;
    if (SPLIT) {
        if (fg < 8) {
            b = reinterpret_cast<const float4*>(ba)[fg];
            dst = reinterpret_cast<float4*>(out) + (size_t)n * 8 + fg;
        } else {
            b = reinterpret_cast<const float4*>(bb)[fg - 8];
            dst = reinterpret_cast<float4*>(out + (size_t)N * 32) + (size_t)n * 8 + (fg - 8);
        }
    } else {
        b = reinterpret_cast<const float4*>(ba)[fg];
        dst = reinterpret_cast<float4*>(out) + (size_t)n * 16 + fg;
    }
    float4 o;
    o.x = fmaf(acc.x, d, b.x); o.y = fmaf(acc.y, d, b.y);
    o.z = fmaf(acc.z, d, b.z); o.w = fmaf(acc.w, d, b.w);
    *dst = o;
}

extern "C" void kernel_launch(void* const* d_in, const int* in_sizes, int n_in,
                              void* d_out, int out_size, void* d_ws, size_t ws_size,
                              hipStream_t stream) {
    const float* x   = (const float*)d_in[0];
    const int*   ei  = (const int*)d_in[1];
    const float* W1  = (const float*)d_in[2];
    const float* b1  = (const float*)d_in[3];
    const float* Wmu = (const float*)d_in[4];
    const float* bmu = (const float*)d_in[5];
    const float* Wls = (const float*)d_in[6];
    const float* bls = (const float*)d_in[7];

    const int N = in_sizes[0] / 128;
    const int E = in_sizes[1] / 2;
    const int* row = ei;       // sources
    const int* col = ei + E;   // targets

    // workspace layout (4B elements): deg N | dinv N | cursor N | srcidx E | t1 64N | agg1 64N
    int*   deg    = (int*)d_ws;
    float* dinv   = (float*)d_ws + N;
    int*   cursor = (int*)d_ws + 2 * (size_t)N;
    int*   srcidx = (int*)d_ws + 3 * (size_t)N;
    float* t1     = (float*)d_ws + 3 * (size_t)N + E;
    float* agg1   = t1 + 64 * (size_t)N;
    float* t2     = t1;  // t1 dead after gather1
    float* outp   = (float*)d_out;

    hipMemsetAsync(deg, 0, (size_t)N * sizeof(int), stream);
    k_count_deg<<<(E + BLK - 1) / BLK, BLK, 0, stream>>>(col, E, deg);
    k_dinv<<<(N + BLK - 1) / BLK, BLK, 0, stream>>>(deg, dinv, N);
    k_scan<<<1, 1024, 0, stream>>>(deg, cursor, N);
    k_bucket<<<(E + BLK - 1) / BLK, BLK, 0, stream>>>(row, col, cursor, srcidx, E);

    k_gemm<128, false, false><<<(N + 31) / 32, 256, 0, stream>>>(x, W1, nullptr, dinv, t1, N);
    k_gather<false><<<(N * 16 + BLK - 1) / BLK, BLK, 0, stream>>>(
        cursor, srcidx, t1, dinv, b1, nullptr, agg1, N);

    k_gemm<64, true, true><<<(N + 31) / 32, 256, 0, stream>>>(agg1, Wmu, Wls, dinv, t2, N);
    k_gather<true><<<(N * 16 + BLK - 1) / BLK, BLK, 0, stream>>>(
        cursor, srcidx, t2, dinv, bmu, bls, outp, N);
}

// Round 3
// 299.884 us; speedup vs baseline: 9.4768x; 1.7510x over previous
//
#include <hip/hip_runtime.h>
#include <hip/hip_bf16.h>

// GCN VGAE encoder, fp32. CSR built via hierarchical (coarse->fine) counting sort,
// atomic-free feature aggregation by gather.
// norm factorization: agg[c] = dinv[c]*(sum_e ts[src] + ts[c]) + b, ts = (X@W)*dinv.

constexpr int BLK = 256;
constexpr int SH = 6;            // nodes per coarse bucket = 64
constexpr int CHUNK = 8192;      // edges per block in coarse passes
constexpr int BMAX = 1024;       // max coarse buckets (N <= 65536)

__device__ __forceinline__ void fma4(float4& a, float s, const float4& w) {
    a.x = fmaf(s, w.x, a.x);
    a.y = fmaf(s, w.y, a.y);
    a.z = fmaf(s, w.z, a.z);
    a.w = fmaf(s, w.w, a.w);
}

// Per-block LDS histogram of col>>SH, flushed with global atomics.
__global__ __launch_bounds__(256) void k_coarse_count(const int* __restrict__ col, int E,
                                                      int* __restrict__ ccnt, int B) {
    __shared__ int h[BMAX];
    const int tid = threadIdx.x;
    for (int i = tid; i < B; i += 256) h[i] = 0;
    __syncthreads();
    const int e0 = blockIdx.x * CHUNK;
    const int e1 = min(e0 + CHUNK, E);
    for (int e = e0 + tid; e < e1; e += 256) atomicAdd(&h[col[e] >> SH], 1);
    __syncthreads();
    for (int i = tid; i < B; i += 256)
        if (h[i]) atomicAdd(&ccnt[i], h[i]);
}

// One block: exclusive scan over B<=1024 coarse counts -> cbase (and ccur copy).
__global__ __launch_bounds__(1024) void k_coarse_scan(const int* __restrict__ ccnt,
                                                      int* __restrict__ cbase,
                                                      int* __restrict__ ccur, int B) {
    __shared__ int sh[16];
    const int tid = threadIdx.x;
    const int lane = tid & 63, wid = tid >> 6;
    int v = (tid < B) ? ccnt[tid] : 0;
    int s = v;
    #pragma unroll
    for (int off = 1; off < 64; off <<= 1) {
        int u = __shfl_up(s, off, 64);
        if (lane >= off) s += u;
    }
    if (lane == 63) sh[wid] = s;
    __syncthreads();
    if (tid < 16) {
        int w = sh[tid];
        #pragma unroll
        for (int off = 1; off < 16; off <<= 1) {
            int u = __shfl_up(w, off, 16);
            if (tid >= off) w += u;
        }
        sh[tid] = w;
    }
    __syncthreads();
    int excl = (wid > 0 ? sh[wid - 1] : 0) + s - v;
    if (tid < B) {
        cbase[tid] = excl;
        ccur[tid] = excl;
    }
}

// Bucket-major emit: per-block LDS hist, one global atomic per (block,bucket) to
// reserve a contiguous slice, then packed int2(row,col) writes.
__global__ __launch_bounds__(256) void k_coarse_scatter(const int* __restrict__ row,
                                                        const int* __restrict__ col,
                                                        int* __restrict__ ccur,
                                                        int2* __restrict__ binned,
                                                        int E, int B) {
    __shared__ int h[BMAX];
    const int tid = threadIdx.x;
    for (int i = tid; i < B; i += 256) h[i] = 0;
    __syncthreads();
    const int e0 = blockIdx.x * CHUNK;
    const int e1 = min(e0 + CHUNK, E);
    for (int e = e0 + tid; e < e1; e += 256) atomicAdd(&h[col[e] >> SH], 1);
    __syncthreads();
    for (int i = tid; i < B; i += 256) {
        int c = h[i];
        if (c) h[i] = atomicAdd(&ccur[i], c);
    }
    __syncthreads();
    for (int e = e0 + tid; e < e1; e += 256) {
        int c = col[e];
        int pos = atomicAdd(&h[c >> SH], 1);
        binned[pos] = make_int2(row[e], c);
    }
}

// One block per bucket: fine histogram (-> deg -> dinv, cursor-end), wave scan for
// per-node CSR bases (coarse_base is already the global prefix), dense srcidx emit.
__global__ __launch_bounds__(256) void k_fine(const int2* __restrict__ binned,
                                              const int* __restrict__ cbase,
                                              const int* __restrict__ ccnt,
                                              int* __restrict__ srcidx,
                                              int* __restrict__ cursor,
                                              float* __restrict__ dinv, int N) {
    __shared__ int fine[64];
    const int b = blockIdx.x;
    const int n0 = b << SH;
    const int estart = cbase[b];
    const int ecnt = ccnt[b];
    const int tid = threadIdx.x;
    if (tid < 64) fine[tid] = 0;
    __syncthreads();
    for (int i = tid; i < ecnt; i += 256)
        atomicAdd(&fine[binned[estart + i].y - n0], 1);
    __syncthreads();
    if (tid < 64) {
        int v = fine[tid], s = v;
        #pragma unroll
        for (int off = 1; off < 64; off <<= 1) {
            int u = __shfl_up(s, off, 64);
            if (tid >= off) s += u;
        }
        int base = estart + s - v;
        int n = n0 + tid;
        if (n < N) {
            cursor[n] = base + v;   // CSR end; start = cursor[n-1]
            dinv[n] = rsqrtf((float)v + 1.0f);
        }
        fine[tid] = base;
    }
    __syncthreads();
    for (int i = tid; i < ecnt; i += 256) {
        int2 e = binned[estart + i];
        int pos = atomicAdd(&fine[e.y - n0], 1);
        srcidx[pos] = e.x;
    }
}

// T[N,64] = (op(X[N,K]) @ W) * dinv[n]   (W = Wa[K,64] or [Wa|Wb], Wa,Wb [K,32])
template <int K, bool RELU, bool TWO_W>
__global__ __launch_bounds__(256) void k_gemm(const float* __restrict__ X,
                                              const float* __restrict__ Wa,
                                              const float* __restrict__ Wb,
                                              const float* __restrict__ dinv,
                                              float* __restrict__ T, int N) {
    __shared__ float4 Wl[K * 16];
    const int tid = threadIdx.x;
    for (int i = tid; i < K * 16; i += 256) {
        if (TWO_W) {
            int k = i >> 4, fg = i & 15;
            const float* s = (fg < 8) ? (Wa + k * 32 + fg * 4)
                                      : (Wb + k * 32 + (fg - 8) * 4);
            Wl[i] = *reinterpret_cast<const float4*>(s);
        } else {
            Wl[i] = reinterpret_cast<const float4*>(Wa)[i];
        }
    }
    __syncthreads();

    const int fg = tid & 15;
    const int ns = tid >> 4;
    const int n0 = blockIdx.x * 32 + ns;
    const int n1 = n0 + 16;
    const bool v0 = n0 < N, v1 = n1 < N;
    const float4* Xv = reinterpret_cast<const float4*>(X);
    const float4 z = make_float4(0.f, 0.f, 0.f, 0.f);
    float4 a0 = z, a1 = z;

    for (int k4 = 0; k4 < K / 4; ++k4) {
        float4 x0 = v0 ? Xv[n0 * (K / 4) + k4] : z;
        float4 x1 = v1 ? Xv[n1 * (K / 4) + k4] : z;
        if (RELU) {
            x0.x = fmaxf(x0.x, 0.f); x0.y = fmaxf(x0.y, 0.f);
            x0.z = fmaxf(x0.z, 0.f); x0.w = fmaxf(x0.w, 0.f);
            x1.x = fmaxf(x1.x, 0.f); x1.y = fmaxf(x1.y, 0.f);
            x1.z = fmaxf(x1.z, 0.f); x1.w = fmaxf(x1.w, 0.f);
        }
        float4 w0 = Wl[(k4 * 4 + 0) * 16 + fg];
        float4 w1 = Wl[(k4 * 4 + 1) * 16 + fg];
        float4 w2 = Wl[(k4 * 4 + 2) * 16 + fg];
        float4 w3 = Wl[(k4 * 4 + 3) * 16 + fg];
        fma4(a0, x0.x, w0); fma4(a0, x0.y, w1); fma4(a0, x0.z, w2); fma4(a0, x0.w, w3);
        fma4(a1, x1.x, w0); fma4(a1, x1.y, w1); fma4(a1, x1.z, w2); fma4(a1, x1.w, w3);
    }
    if (v0) {
        float d = dinv[n0];
        a0.x *= d; a0.y *= d; a0.z *= d; a0.w *= d;
        reinterpret_cast<float4*>(T)[n0 * 16 + fg] = a0;
    }
    if (v1) {
        float d = dinv[n1];
        a1.x *= d; a1.y *= d; a1.z *= d; a1.w *= d;
        reinterpret_cast<float4*>(T)[n1 * 16 + fg] = a1;
    }
}

// out[n] = dinv[n]*(sum_{k in [cur[n-1],cur[n])} Ts[srcidx[k]] + Ts[n]) + bias
// 16 threads/node, float4 each. SPLIT routes feats 0:32 -> out, 32:64 -> out+32N.
template <bool SPLIT>
__global__ __launch_bounds__(256) void k_gather(const int* __restrict__ cursor,
                                                const int* __restrict__ srcidx,
                                                const float* __restrict__ Ts,
                                                const float* __restrict__ dinv,
                                                const float* __restrict__ ba,
                                                const float* __restrict__ bb,
                                                float* __restrict__ out, int N) {
    int g = blockIdx.x * BLK + threadIdx.x;
    int n = g >> 4, fg = g & 15;
    if (n >= N) return;
    int start = (n == 0) ? 0 : cursor[n - 1];
    int end = cursor[n];
    const float4* Tv = reinterpret_cast<const float4*>(Ts);
    float4 acc = Tv[n * 16 + fg];   // self loop
    int k = start;
    for (; k + 1 < end; k += 2) {
        int r0 = srcidx[k], r1 = srcidx[k + 1];
        float4 v0 = Tv[r0 * 16 + fg];
        float4 v1 = Tv[r1 * 16 + fg];
        acc.x += v0.x + v1.x; acc.y += v0.y + v1.y;
        acc.z += v0.z + v1.z; acc.w += v0.w + v1.w;
    }
    if (k < end) {
        float4 v0 = Tv[srcidx[k] * 16 + fg];
        acc.x += v0.x; acc.y += v0.y; acc.z += v0.z; acc.w += v0.w;
    }
    float d = dinv[n];
    float4 b;
    float4* dst;
    if (SPLIT) {
        if (fg < 8) {
            b = reinterpret_cast<const float4*>(ba)[fg];
            dst = reinterpret_cast<float4*>(out) + (size_t)n * 8 + fg;
        } else {
            b = reinterpret_cast<const float4*>(bb)[fg - 8];
            dst = reinterpret_cast<float4*>(out + (size_t)N * 32) + (size_t)n * 8 + (fg - 8);
        }
    } else {
        b = reinterpret_cast<const float4*>(ba)[fg];
        dst = reinterpret_cast<float4*>(out) + (size_t)n * 16 + fg;
    }
    float4 o;
    o.x = fmaf(acc.x, d, b.x); o.y = fmaf(acc.y, d, b.y);
    o.z = fmaf(acc.z, d, b.z); o.w = fmaf(acc.w, d, b.w);
    *dst = o;
}

extern "C" void kernel_launch(void* const* d_in, const int* in_sizes, int n_in,
                              void* d_out, int out_size, void* d_ws, size_t ws_size,
                              hipStream_t stream) {
    const float* x   = (const float*)d_in[0];
    const int*   ei  = (const int*)d_in[1];
    const float* W1  = (const float*)d_in[2];
    const float* b1  = (const float*)d_in[3];
    const float* Wmu = (const float*)d_in[4];
    const float* bmu = (const float*)d_in[5];
    const float* Wls = (const float*)d_in[6];
    const float* bls = (const float*)d_in[7];

    const int N = in_sizes[0] / 128;
    const int E = in_sizes[1] / 2;
    const int* row = ei;       // sources
    const int* col = ei + E;   // targets
    const int B = (N + 63) >> SH;   // coarse buckets (<= BMAX)

    // ws layout (4B units):
    // [0,1024)        ccnt
    // [1024,2048)     cbase
    // [2048,3072)     ccur
    // [3072, +ov)     binned int2[E]  (overlaid by t1[64N] after k_fine)
    // then srcidx[E], dinv[N], cursor[N], agg1[64N]
    int* wsi = (int*)d_ws;
    int*  ccnt   = wsi;
    int*  cbase  = wsi + 1024;
    int*  ccur   = wsi + 2048;
    int2* binned = (int2*)(wsi + 3072);
    float* t1    = (float*)(wsi + 3072);          // overlays binned
    size_t ov    = (size_t)2 * E;
    if ((size_t)64 * N > ov) ov = (size_t)64 * N;
    int*  srcidx = wsi + 3072 + ov;
    float* dinv  = (float*)(srcidx + E);
    int*  cursor = (int*)(dinv + N);
    float* agg1  = (float*)(cursor + N);
    float* t2    = t1;                            // t1 dead after gather1
    float* outp  = (float*)d_out;

    const int G = (E + CHUNK - 1) / CHUNK;

    hipMemsetAsync(ccnt, 0, 1024 * sizeof(int), stream);
    k_coarse_count<<<G, 256, 0, stream>>>(col, E, ccnt, B);
    k_coarse_scan<<<1, 1024, 0, stream>>>(ccnt, cbase, ccur, B);
    k_coarse_scatter<<<G, 256, 0, stream>>>(row, col, ccur, binned, E, B);
    k_fine<<<B, 256, 0, stream>>>(binned, cbase, ccnt, srcidx, cursor, dinv, N);

    k_gemm<128, false, false><<<(N + 31) / 32, 256, 0, stream>>>(x, W1, nullptr, dinv, t1, N);
    k_gather<false><<<(N * 16 + BLK - 1) / BLK, BLK, 0, stream>>>(
        cursor, srcidx, t1, dinv, b1, nullptr, agg1, N);

    k_gemm<64, true, true><<<(N + 31) / 32, 256, 0, stream>>>(agg1, Wmu, Wls, dinv, t2, N);
    k_gather<true><<<(N * 16 + BLK - 1) / BLK, BLK, 0, stream>>>(
        cursor, srcidx, t2, dinv, bmu, bls, outp, N);
}

// Round 4
// 240.208 us; speedup vs baseline: 11.8311x; 1.2484x over previous
//
#include <hip/hip_runtime.h>
#include <hip/hip_bf16.h>

// GCN VGAE encoder. CSR via hierarchical counting sort (packed uint bins),
// gather aggregation over a bf16 ts table (fp32 accumulate).
// norm factorization: agg[c] = dinv[c]*(sum_e ts[src] + ts[c]) + b, ts = (X@W)*dinv.

constexpr int BLK = 256;
constexpr int SH = 6;            // nodes per coarse bucket = 64
constexpr int CHUNK = 4096;      // edges per block in coarse passes
constexpr int BMAX = 1024;       // max coarse buckets (N <= 65536)

__device__ __forceinline__ void fma4(float4& a, float s, const float4& w) {
    a.x = fmaf(s, w.x, a.x);
    a.y = fmaf(s, w.y, a.y);
    a.z = fmaf(s, w.z, a.z);
    a.w = fmaf(s, w.w, a.w);
}

__device__ __forceinline__ unsigned short f2bf(float f) {  // RNE, no NaN handling
    unsigned u = __float_as_uint(f);
    return (unsigned short)((u + 0x7fffu + ((u >> 16) & 1u)) >> 16);
}

__device__ __forceinline__ void acc_bf8(float* a, uint4 v) {
    a[0] += __uint_as_float(v.x << 16);
    a[1] += __uint_as_float(v.x & 0xffff0000u);
    a[2] += __uint_as_float(v.y << 16);
    a[3] += __uint_as_float(v.y & 0xffff0000u);
    a[4] += __uint_as_float(v.z << 16);
    a[5] += __uint_as_float(v.z & 0xffff0000u);
    a[6] += __uint_as_float(v.w << 16);
    a[7] += __uint_as_float(v.w & 0xffff0000u);
}

// Per-block LDS histogram of col>>SH, flushed with global atomics.
__global__ __launch_bounds__(256) void k_coarse_count(const int* __restrict__ col, int E,
                                                      int* __restrict__ ccnt, int B) {
    __shared__ int h[BMAX];
    const int tid = threadIdx.x;
    for (int i = tid; i < B; i += 256) h[i] = 0;
    __syncthreads();
    const int e0 = blockIdx.x * CHUNK;
    const int e1 = min(e0 + CHUNK, E);
    for (int e = e0 + tid; e < e1; e += 256) atomicAdd(&h[col[e] >> SH], 1);
    __syncthreads();
    for (int i = tid; i < B; i += 256)
        if (h[i]) atomicAdd(&ccnt[i], h[i]);
}

// One block: exclusive scan over B<=1024 coarse counts -> cbase (and ccur copy).
__global__ __launch_bounds__(1024) void k_coarse_scan(const int* __restrict__ ccnt,
                                                      int* __restrict__ cbase,
                                                      int* __restrict__ ccur, int B) {
    __shared__ int sh[16];
    const int tid = threadIdx.x;
    const int lane = tid & 63, wid = tid >> 6;
    int v = (tid < B) ? ccnt[tid] : 0;
    int s = v;
    #pragma unroll
    for (int off = 1; off < 64; off <<= 1) {
        int u = __shfl_up(s, off, 64);
        if (lane >= off) s += u;
    }
    if (lane == 63) sh[wid] = s;
    __syncthreads();
    if (tid < 16) {
        int w = sh[tid];
        #pragma unroll
        for (int off = 1; off < 16; off <<= 1) {
            int u = __shfl_up(w, off, 16);
            if (tid >= off) w += u;
        }
        sh[tid] = w;
    }
    __syncthreads();
    int excl = (wid > 0 ? sh[wid - 1] : 0) + s - v;
    if (tid < B) {
        cbase[tid] = excl;
        ccur[tid] = excl;
    }
}

// Bucket-major emit: per-block LDS hist, one global atomic per (block,bucket) to
// reserve a contiguous slice, then packed uint (fine<<26 | src) writes.
__global__ __launch_bounds__(256) void k_coarse_scatter(const int* __restrict__ row,
                                                        const int* __restrict__ col,
                                                        int* __restrict__ ccur,
                                                        unsigned* __restrict__ binned,
                                                        int E, int B) {
    __shared__ int h[BMAX];
    const int tid = threadIdx.x;
    for (int i = tid; i < B; i += 256) h[i] = 0;
    __syncthreads();
    const int e0 = blockIdx.x * CHUNK;
    const int e1 = min(e0 + CHUNK, E);
    for (int e = e0 + tid; e < e1; e += 256) atomicAdd(&h[col[e] >> SH], 1);
    __syncthreads();
    for (int i = tid; i < B; i += 256) {
        int c = h[i];
        if (c) h[i] = atomicAdd(&ccur[i], c);
    }
    __syncthreads();
    for (int e = e0 + tid; e < e1; e += 256) {
        int c = col[e];
        int pos = atomicAdd(&h[c >> SH], 1);
        binned[pos] = (unsigned)row[e] | ((unsigned)(c & 63) << 26);
    }
}

// One block per bucket: fine histogram (-> dinv, cursor-end), wave scan for
// per-node CSR bases (coarse base is already the global prefix), dense srcidx emit.
__global__ __launch_bounds__(256) void k_fine(const unsigned* __restrict__ binned,
                                              const int* __restrict__ cbase,
                                              const int* __restrict__ ccnt,
                                              int* __restrict__ srcidx,
                                              int* __restrict__ cursor,
                                              float* __restrict__ dinv, int N) {
    __shared__ int fine[64];
    const int b = blockIdx.x;
    const int n0 = b << SH;
    const int estart = cbase[b];
    const int ecnt = ccnt[b];
    const int tid = threadIdx.x;
    if (tid < 64) fine[tid] = 0;
    __syncthreads();
    for (int i = tid; i < ecnt; i += 256)
        atomicAdd(&fine[binned[estart + i] >> 26], 1);
    __syncthreads();
    if (tid < 64) {
        int v = fine[tid], s = v;
        #pragma unroll
        for (int off = 1; off < 64; off <<= 1) {
            int u = __shfl_up(s, off, 64);
            if (tid >= off) s += u;
        }
        int base = estart + s - v;
        int n = n0 + tid;
        if (n < N) {
            cursor[n] = base + v;   // CSR end; start = cursor[n-1]
            dinv[n] = rsqrtf((float)v + 1.0f);
        }
        fine[tid] = base;
    }
    __syncthreads();
    for (int i = tid; i < ecnt; i += 256) {
        unsigned e = binned[estart + i];
        int pos = atomicAdd(&fine[e >> 26], 1);
        srcidx[pos] = (int)(e & 0x03FFFFFFu);
    }
}

// T[N,64](bf16) = (op(X[N,K]) @ W) * dinv[n]   (W = Wa[K,64] or [Wa|Wb], Wa,Wb [K,32])
template <int K, bool RELU, bool TWO_W>
__global__ __launch_bounds__(256) void k_gemm(const float* __restrict__ X,
                                              const float* __restrict__ Wa,
                                              const float* __restrict__ Wb,
                                              const float* __restrict__ dinv,
                                              unsigned short* __restrict__ T, int N) {
    __shared__ float4 Wl[K * 16];
    const int tid = threadIdx.x;
    for (int i = tid; i < K * 16; i += 256) {
        if (TWO_W) {
            int k = i >> 4, fg = i & 15;
            const float* s = (fg < 8) ? (Wa + k * 32 + fg * 4)
                                      : (Wb + k * 32 + (fg - 8) * 4);
            Wl[i] = *reinterpret_cast<const float4*>(s);
        } else {
            Wl[i] = reinterpret_cast<const float4*>(Wa)[i];
        }
    }
    __syncthreads();

    const int fg = tid & 15;
    const int ns = tid >> 4;
    const int n0 = blockIdx.x * 32 + ns;
    const int n1 = n0 + 16;
    const bool v0 = n0 < N, v1 = n1 < N;
    const float4* Xv = reinterpret_cast<const float4*>(X);
    const float4 z = make_float4(0.f, 0.f, 0.f, 0.f);
    float4 a0 = z, a1 = z;

    for (int k4 = 0; k4 < K / 4; ++k4) {
        float4 x0 = v0 ? Xv[n0 * (K / 4) + k4] : z;
        float4 x1 = v1 ? Xv[n1 * (K / 4) + k4] : z;
        if (RELU) {
            x0.x = fmaxf(x0.x, 0.f); x0.y = fmaxf(x0.y, 0.f);
            x0.z = fmaxf(x0.z, 0.f); x0.w = fmaxf(x0.w, 0.f);
            x1.x = fmaxf(x1.x, 0.f); x1.y = fmaxf(x1.y, 0.f);
            x1.z = fmaxf(x1.z, 0.f); x1.w = fmaxf(x1.w, 0.f);
        }
        float4 w0 = Wl[(k4 * 4 + 0) * 16 + fg];
        float4 w1 = Wl[(k4 * 4 + 1) * 16 + fg];
        float4 w2 = Wl[(k4 * 4 + 2) * 16 + fg];
        float4 w3 = Wl[(k4 * 4 + 3) * 16 + fg];
        fma4(a0, x0.x, w0); fma4(a0, x0.y, w1); fma4(a0, x0.z, w2); fma4(a0, x0.w, w3);
        fma4(a1, x1.x, w0); fma4(a1, x1.y, w1); fma4(a1, x1.z, w2); fma4(a1, x1.w, w3);
    }
    if (v0) {
        float d = dinv[n0];
        ushort4 o;
        o.x = f2bf(a0.x * d); o.y = f2bf(a0.y * d);
        o.z = f2bf(a0.z * d); o.w = f2bf(a0.w * d);
        reinterpret_cast<ushort4*>(T)[n0 * 16 + fg] = o;
    }
    if (v1) {
        float d = dinv[n1];
        ushort4 o;
        o.x = f2bf(a1.x * d); o.y = f2bf(a1.y * d);
        o.z = f2bf(a1.z * d); o.w = f2bf(a1.w * d);
        reinterpret_cast<ushort4*>(T)[n1 * 16 + fg] = o;
    }
}

// out[n] = dinv[n]*(sum_{k in csr(n)} Ts[srcidx[k]] + Ts[n]) + bias
// 8 threads/node, 16 B (8 bf16 feats) each, fp32 accumulate, 4-edge unroll.
// SPLIT routes feats 0:32 -> out (mu), 32:64 -> out+32N (logstd).
template <bool SPLIT>
__global__ __launch_bounds__(256) void k_gather(const int* __restrict__ cursor,
                                                const int* __restrict__ srcidx,
                                                const uint4* __restrict__ Ts,
                                                const float* __restrict__ dinv,
                                                const float* __restrict__ ba,
                                                const float* __restrict__ bb,
                                                float* __restrict__ out, int N) {
    int g = blockIdx.x * BLK + threadIdx.x;
    int n = g >> 3, fg = g & 7;
    if (n >= N) return;
    int start = (n == 0) ? 0 : cursor[n - 1];
    int end = cursor[n];
    float a[8];
    {
        uint4 s = Ts[(size_t)n * 8 + fg];   // self loop
        a[0] = __uint_as_float(s.x << 16);
        a[1] = __uint_as_float(s.x & 0xffff0000u);
        a[2] = __uint_as_float(s.y << 16);
        a[3] = __uint_as_float(s.y & 0xffff0000u);
        a[4] = __uint_as_float(s.z << 16);
        a[5] = __uint_as_float(s.z & 0xffff0000u);
        a[6] = __uint_as_float(s.w << 16);
        a[7] = __uint_as_float(s.w & 0xffff0000u);
    }
    int k = start;
    for (; k + 4 <= end; k += 4) {
        int r0 = srcidx[k], r1 = srcidx[k + 1], r2 = srcidx[k + 2], r3 = srcidx[k + 3];
        uint4 v0 = Ts[(size_t)r0 * 8 + fg];
        uint4 v1 = Ts[(size_t)r1 * 8 + fg];
        uint4 v2 = Ts[(size_t)r2 * 8 + fg];
        uint4 v3 = Ts[(size_t)r3 * 8 + fg];
        acc_bf8(a, v0); acc_bf8(a, v1); acc_bf8(a, v2); acc_bf8(a, v3);
    }
    for (; k < end; ++k)
        acc_bf8(a, Ts[(size_t)srcidx[k] * 8 + fg]);

    float d = dinv[n];
    const float* bsrc;
    float* dst;
    if (SPLIT) {
        if (fg < 4) {
            bsrc = ba + fg * 8;
            dst = out + (size_t)n * 32 + fg * 8;
        } else {
            bsrc = bb + (fg - 4) * 8;
            dst = out + (size_t)N * 32 + (size_t)n * 32 + (fg - 4) * 8;
        }
    } else {
        bsrc = ba + fg * 8;
        dst = out + (size_t)n * 64 + fg * 8;
    }
    float4 b0 = reinterpret_cast<const float4*>(bsrc)[0];
    float4 b1 = reinterpret_cast<const float4*>(bsrc)[1];
    float4 o0, o1;
    o0.x = fmaf(a[0], d, b0.x); o0.y = fmaf(a[1], d, b0.y);
    o0.z = fmaf(a[2], d, b0.z); o0.w = fmaf(a[3], d, b0.w);
    o1.x = fmaf(a[4], d, b1.x); o1.y = fmaf(a[5], d, b1.y);
    o1.z = fmaf(a[6], d, b1.z); o1.w = fmaf(a[7], d, b1.w);
    reinterpret_cast<float4*>(dst)[0] = o0;
    reinterpret_cast<float4*>(dst)[1] = o1;
}

extern "C" void kernel_launch(void* const* d_in, const int* in_sizes, int n_in,
                              void* d_out, int out_size, void* d_ws, size_t ws_size,
                              hipStream_t stream) {
    const float* x   = (const float*)d_in[0];
    const int*   ei  = (const int*)d_in[1];
    const float* W1  = (const float*)d_in[2];
    const float* b1  = (const float*)d_in[3];
    const float* Wmu = (const float*)d_in[4];
    const float* bmu = (const float*)d_in[5];
    const float* Wls = (const float*)d_in[6];
    const float* bls = (const float*)d_in[7];

    const int N = in_sizes[0] / 128;
    const int E = in_sizes[1] / 2;
    const int* row = ei;       // sources
    const int* col = ei + E;   // targets
    const int B = (N + 63) >> SH;   // coarse buckets (<= BMAX)

    // ws layout (4B units):
    // [0,1024) ccnt | [1024,2048) cbase | [2048,3072) ccur
    // [3072,+ov) binned uint[E] (overlaid by t1 bf16[64N] = 32N ints after k_fine)
    // then srcidx[E] | dinv[N] | cursor[N] | agg1 f32[64N]
    int* wsi = (int*)d_ws;
    int*  ccnt   = wsi;
    int*  cbase  = wsi + 1024;
    int*  ccur   = wsi + 2048;
    unsigned* binned = (unsigned*)(wsi + 3072);
    unsigned short* t1 = (unsigned short*)(wsi + 3072);   // overlays binned
    size_t ov = (size_t)E;
    if ((size_t)32 * N > ov) ov = (size_t)32 * N;
    int*  srcidx = wsi + 3072 + ov;
    float* dinv  = (float*)(srcidx + E);
    int*  cursor = (int*)(dinv + N);
    float* agg1  = (float*)(cursor + N);
    unsigned short* t2 = t1;                              // t1 dead after gather1
    float* outp  = (float*)d_out;

    const int G = (E + CHUNK - 1) / CHUNK;

    hipMemsetAsync(ccnt, 0, 1024 * sizeof(int), stream);
    k_coarse_count<<<G, 256, 0, stream>>>(col, E, ccnt, B);
    k_coarse_scan<<<1, 1024, 0, stream>>>(ccnt, cbase, ccur, B);
    k_coarse_scatter<<<G, 256, 0, stream>>>(row, col, ccur, binned, E, B);
    k_fine<<<B, 256, 0, stream>>>(binned, cbase, ccnt, srcidx, cursor, dinv, N);

    k_gemm<128, false, false><<<(N + 31) / 32, 256, 0, stream>>>(x, W1, nullptr, dinv, t1, N);
    k_gather<false><<<(N * 8 + BLK - 1) / BLK, BLK, 0, stream>>>(
        cursor, srcidx, (const uint4*)t1, dinv, b1, nullptr, agg1, N);

    k_gemm<64, true, true><<<(N + 31) / 32, 256, 0, stream>>>(agg1, Wmu, Wls, dinv, t2, N);
    k_gather<true><<<(N * 8 + BLK - 1) / BLK, BLK, 0, stream>>>(
        cursor, srcidx, (const uint4*)t2, dinv, bmu, bls, outp, N);
}

// Round 5
// 237.637 us; speedup vs baseline: 11.9591x; 1.0108x over previous
//
#include <hip/hip_runtime.h>
#include <hip/hip_bf16.h>

// GCN VGAE encoder. CSR via single-pass fixed-capacity bucket binning
// (no count/scan passes), gather aggregation over a bf16 ts table (fp32 accum).
// norm factorization: agg[c] = dinv[c]*(sum_e ts[src] + ts[c]) + b, ts = (X@W)*dinv.

constexpr int BLK = 256;
constexpr int SH = 6;            // nodes per coarse bucket = 64
constexpr int CAP = 4096;        // slab capacity per bucket (mean ~2046, 45 sigma)
constexpr int CHUNK = 4096;      // edges per block in k_bin
constexpr int BMAX = 1024;       // max coarse buckets (N <= 65536)
constexpr int EPT = 10;          // register-cached edges per thread in k_fine

__device__ __forceinline__ void fma4(float4& a, float s, const float4& w) {
    a.x = fmaf(s, w.x, a.x);
    a.y = fmaf(s, w.y, a.y);
    a.z = fmaf(s, w.z, a.z);
    a.w = fmaf(s, w.w, a.w);
}

__device__ __forceinline__ unsigned short f2bf(float f) {  // RNE
    unsigned u = __float_as_uint(f);
    return (unsigned short)((u + 0x7fffu + ((u >> 16) & 1u)) >> 16);
}

__device__ __forceinline__ void acc_bf8(float* a, uint4 v) {
    a[0] += __uint_as_float(v.x << 16);
    a[1] += __uint_as_float(v.x & 0xffff0000u);
    a[2] += __uint_as_float(v.y << 16);
    a[3] += __uint_as_float(v.y & 0xffff0000u);
    a[4] += __uint_as_float(v.z << 16);
    a[5] += __uint_as_float(v.z & 0xffff0000u);
    a[6] += __uint_as_float(v.w << 16);
    a[7] += __uint_as_float(v.w & 0xffff0000u);
}

// Single-pass binning: LDS hist -> reserve slab slice via ccur atomic -> packed emit.
// binned entry: (col&63)<<26 | row. Slab base for bucket b is b*CAP.
__global__ __launch_bounds__(256) void k_bin(const int* __restrict__ row,
                                             const int* __restrict__ col,
                                             int* __restrict__ ccur,
                                             unsigned* __restrict__ binned,
                                             int E, int B) {
    __shared__ int h[BMAX];
    const int tid = threadIdx.x;
    for (int i = tid; i < B; i += 256) h[i] = 0;
    __syncthreads();
    const int e0 = blockIdx.x * CHUNK;
    const int e1 = min(e0 + CHUNK, E);
    for (int e = e0 + tid; e < e1; e += 256) atomicAdd(&h[col[e] >> SH], 1);
    __syncthreads();
    for (int i = tid; i < B; i += 256) {
        int c = h[i];
        if (c) h[i] = atomicAdd(&ccur[i], c);   // in-bucket base for this block
    }
    __syncthreads();
    for (int e = e0 + tid; e < e1; e += 256) {
        int c = col[e];
        int b = c >> SH;
        int pos = atomicAdd(&h[b], 1);
        if (pos < CAP)
            binned[(size_t)b * CAP + pos] = (unsigned)row[e] | ((unsigned)(c & 63) << 26);
    }
}

// One block per bucket: register-cached edges; fine histogram -> dinv + (start,end)
// ranges; dense srcidx emit into the bucket's fixed-cap slab.
__global__ __launch_bounds__(256) void k_fine(const unsigned* __restrict__ binned,
                                              const int* __restrict__ ccur,
                                              int* __restrict__ srcidx,
                                              int2* __restrict__ range2,
                                              float* __restrict__ dinv, int N) {
    __shared__ int fine[64];
    const int b = blockIdx.x;
    const int n0 = b << SH;
    const int ebase = b * CAP;
    int ecnt = ccur[b];
    if (ecnt > CAP) ecnt = CAP;
    const int tid = threadIdx.x;
    if (tid < 64) fine[tid] = 0;
    __syncthreads();
    unsigned ebuf[EPT];
    #pragma unroll
    for (int j = 0; j < EPT; ++j) {
        int i = tid + j * 256;
        ebuf[j] = (i < ecnt) ? binned[ebase + i] : 0xffffffffu;
    }
    #pragma unroll
    for (int j = 0; j < EPT; ++j)
        if (ebuf[j] != 0xffffffffu) atomicAdd(&fine[ebuf[j] >> 26], 1);
    for (int i = EPT * 256 + tid; i < ecnt; i += 256)   // overflow tail (normally empty)
        atomicAdd(&fine[binned[ebase + i] >> 26], 1);
    __syncthreads();
    if (tid < 64) {
        int v = fine[tid], s = v;
        #pragma unroll
        for (int off = 1; off < 64; off <<= 1) {
            int u = __shfl_up(s, off, 64);
            if (tid >= off) s += u;
        }
        int base = ebase + s - v;
        int n = n0 + tid;
        if (n < N) {
            range2[n] = make_int2(base, base + v);
            dinv[n] = rsqrtf((float)v + 1.0f);
        }
        fine[tid] = base;
    }
    __syncthreads();
    #pragma unroll
    for (int j = 0; j < EPT; ++j) {
        unsigned e = ebuf[j];
        if (e != 0xffffffffu) {
            int pos = atomicAdd(&fine[e >> 26], 1);
            srcidx[pos] = (int)(e & 0x03FFFFFFu);
        }
    }
    for (int i = EPT * 256 + tid; i < ecnt; i += 256) {
        unsigned e = binned[ebase + i];
        int pos = atomicAdd(&fine[e >> 26], 1);
        srcidx[pos] = (int)(e & 0x03FFFFFFu);
    }
}

// T[N,64](bf16) = (op(X[N,K]) @ W) * dinv[n].  4 nodes/thread to amortize LDS W-reads.
template <int K, bool RELU, bool TWO_W>
__global__ __launch_bounds__(256) void k_gemm(const float* __restrict__ X,
                                              const float* __restrict__ Wa,
                                              const float* __restrict__ Wb,
                                              const float* __restrict__ dinv,
                                              unsigned short* __restrict__ T, int N) {
    __shared__ float4 Wl[K * 16];
    const int tid = threadIdx.x;
    for (int i = tid; i < K * 16; i += 256) {
        if (TWO_W) {
            int k = i >> 4, fgi = i & 15;
            const float* s = (fgi < 8) ? (Wa + k * 32 + fgi * 4)
                                       : (Wb + k * 32 + (fgi - 8) * 4);
            Wl[i] = *reinterpret_cast<const float4*>(s);
        } else {
            Wl[i] = reinterpret_cast<const float4*>(Wa)[i];
        }
    }
    __syncthreads();

    const int fg = tid & 15;
    const int ns = tid >> 4;
    const int nb = blockIdx.x * 64;
    const float4* Xv = reinterpret_cast<const float4*>(X);
    const float4 z = make_float4(0.f, 0.f, 0.f, 0.f);
    float4 acc[4] = {z, z, z, z};
    int n[4];
    bool v[4];
    #pragma unroll
    for (int i = 0; i < 4; ++i) { n[i] = nb + ns + i * 16; v[i] = n[i] < N; }

    for (int k4 = 0; k4 < K / 4; ++k4) {
        float4 xv[4];
        #pragma unroll
        for (int i = 0; i < 4; ++i) {
            xv[i] = v[i] ? Xv[(size_t)n[i] * (K / 4) + k4] : z;
            if (RELU) {
                xv[i].x = fmaxf(xv[i].x, 0.f); xv[i].y = fmaxf(xv[i].y, 0.f);
                xv[i].z = fmaxf(xv[i].z, 0.f); xv[i].w = fmaxf(xv[i].w, 0.f);
            }
        }
        float4 w0 = Wl[(k4 * 4 + 0) * 16 + fg];
        float4 w1 = Wl[(k4 * 4 + 1) * 16 + fg];
        float4 w2 = Wl[(k4 * 4 + 2) * 16 + fg];
        float4 w3 = Wl[(k4 * 4 + 3) * 16 + fg];
        #pragma unroll
        for (int i = 0; i < 4; ++i) {
            fma4(acc[i], xv[i].x, w0); fma4(acc[i], xv[i].y, w1);
            fma4(acc[i], xv[i].z, w2); fma4(acc[i], xv[i].w, w3);
        }
    }
    #pragma unroll
    for (int i = 0; i < 4; ++i) {
        if (v[i]) {
            float d = dinv[n[i]];
            ushort4 o;
            o.x = f2bf(acc[i].x * d); o.y = f2bf(acc[i].y * d);
            o.z = f2bf(acc[i].z * d); o.w = f2bf(acc[i].w * d);
            reinterpret_cast<ushort4*>(T)[(size_t)n[i] * 16 + fg] = o;
        }
    }
}

// out[n] = dinv[n]*(sum_{k in range(n)} Ts[srcidx[k]] + Ts[n]) + bias
// 8 threads/node, 16 B (8 bf16 feats) each, fp32 accumulate, int4 srcidx loads.
// SPLIT routes feats 0:32 -> out (mu), 32:64 -> out+32N (logstd).
template <bool SPLIT>
__global__ __launch_bounds__(256) void k_gather(const int2* __restrict__ range2,
                                                const int* __restrict__ srcidx,
                                                const uint4* __restrict__ Ts,
                                                const float* __restrict__ dinv,
                                                const float* __restrict__ ba,
                                                const float* __restrict__ bb,
                                                float* __restrict__ out, int N) {
    int g = blockIdx.x * BLK + threadIdx.x;
    int n = g >> 3, fg = g & 7;
    if (n >= N) return;
    int2 rg = range2[n];
    int k = rg.x, end = rg.y;
    float a[8];
    {
        uint4 s = Ts[(size_t)n * 8 + fg];   // self loop
        a[0] = __uint_as_float(s.x << 16);
        a[1] = __uint_as_float(s.x & 0xffff0000u);
        a[2] = __uint_as_float(s.y << 16);
        a[3] = __uint_as_float(s.y & 0xffff0000u);
        a[4] = __uint_as_float(s.z << 16);
        a[5] = __uint_as_float(s.z & 0xffff0000u);
        a[6] = __uint_as_float(s.w << 16);
        a[7] = __uint_as_float(s.w & 0xffff0000u);
    }
    for (; k < end && (k & 3); ++k)          // align to int4
        acc_bf8(a, Ts[(size_t)srcidx[k] * 8 + fg]);
    for (; k + 4 <= end; k += 4) {
        int4 r = *reinterpret_cast<const int4*>(srcidx + k);
        uint4 v0 = Ts[(size_t)r.x * 8 + fg];
        uint4 v1 = Ts[(size_t)r.y * 8 + fg];
        uint4 v2 = Ts[(size_t)r.z * 8 + fg];
        uint4 v3 = Ts[(size_t)r.w * 8 + fg];
        acc_bf8(a, v0); acc_bf8(a, v1); acc_bf8(a, v2); acc_bf8(a, v3);
    }
    for (; k < end; ++k)
        acc_bf8(a, Ts[(size_t)srcidx[k] * 8 + fg]);

    float d = dinv[n];
    const float* bsrc;
    float* dst;
    if (SPLIT) {
        if (fg < 4) {
            bsrc = ba + fg * 8;
            dst = out + (size_t)n * 32 + fg * 8;
        } else {
            bsrc = bb + (fg - 4) * 8;
            dst = out + (size_t)N * 32 + (size_t)n * 32 + (fg - 4) * 8;
        }
    } else {
        bsrc = ba + fg * 8;
        dst = out + (size_t)n * 64 + fg * 8;
    }
    float4 b0 = reinterpret_cast<const float4*>(bsrc)[0];
    float4 b1 = reinterpret_cast<const float4*>(bsrc)[1];
    float4 o0, o1;
    o0.x = fmaf(a[0], d, b0.x); o0.y = fmaf(a[1], d, b0.y);
    o0.z = fmaf(a[2], d, b0.z); o0.w = fmaf(a[3], d, b0.w);
    o1.x = fmaf(a[4], d, b1.x); o1.y = fmaf(a[5], d, b1.y);
    o1.z = fmaf(a[6], d, b1.z); o1.w = fmaf(a[7], d, b1.w);
    reinterpret_cast<float4*>(dst)[0] = o0;
    reinterpret_cast<float4*>(dst)[1] = o1;
}

extern "C" void kernel_launch(void* const* d_in, const int* in_sizes, int n_in,
                              void* d_out, int out_size, void* d_ws, size_t ws_size,
                              hipStream_t stream) {
    const float* x   = (const float*)d_in[0];
    const int*   ei  = (const int*)d_in[1];
    const float* W1  = (const float*)d_in[2];
    const float* b1  = (const float*)d_in[3];
    const float* Wmu = (const float*)d_in[4];
    const float* bmu = (const float*)d_in[5];
    const float* Wls = (const float*)d_in[6];
    const float* bls = (const float*)d_in[7];

    const int N = in_sizes[0] / 128;
    const int E = in_sizes[1] / 2;
    const int* row = ei;            // sources
    const int* col = ei + E;        // targets
    const int B = (N + 63) >> SH;   // coarse buckets (<= BMAX)
    const size_t BCAP = (size_t)B * CAP;

    // ws layout (4B units):
    // [0,1024) ccur | [1024, 1024+BCAP) binned (t1/t2 bf16[64N]=32N ints overlay after k_fine)
    // | srcidx[BCAP] | dinv[N] | range2 int2[N] (2N) | agg1 f32[64N]
    int* wsi = (int*)d_ws;
    int*  ccur   = wsi;
    unsigned* binned = (unsigned*)(wsi + 1024);
    unsigned short* t1 = (unsigned short*)(wsi + 1024);   // overlays binned
    int*  srcidx = wsi + 1024 + BCAP;
    float* dinv  = (float*)(srcidx + BCAP);
    int2* range2 = (int2*)(dinv + N);
    float* agg1  = (float*)(range2 + N);
    unsigned short* t2 = t1;                              // t1 dead before gemm2 writes
    float* outp  = (float*)d_out;

    const int G = (E + CHUNK - 1) / CHUNK;

    hipMemsetAsync(ccur, 0, 1024 * sizeof(int), stream);
    k_bin<<<G, 256, 0, stream>>>(row, col, ccur, binned, E, B);
    k_fine<<<B, 256, 0, stream>>>(binned, ccur, srcidx, range2, dinv, N);

    k_gemm<128, false, false><<<(N + 63) / 64, 256, 0, stream>>>(x, W1, nullptr, dinv, t1, N);
    k_gather<false><<<(N * 8 + BLK - 1) / BLK, BLK, 0, stream>>>(
        range2, srcidx, (const uint4*)t1, dinv, b1, nullptr, agg1, N);

    k_gemm<64, true, true><<<(N + 63) / 64, 256, 0, stream>>>(agg1, Wmu, Wls, dinv, t2, N);
    k_gather<true><<<(N * 8 + BLK - 1) / BLK, BLK, 0, stream>>>(
        range2, srcidx, (const uint4*)t2, dinv, bmu, bls, outp, N);
}

// Round 7
// 234.596 us; speedup vs baseline: 12.1141x; 1.0130x over previous
//
#include <hip/hip_runtime.h>
#include <hip/hip_bf16.h>

// GCN VGAE encoder. CSR via single-pass register-cached bucket binning,
// ushort adjacency, gather aggregation over bf16 ts table (fp32 accum).
// norm factorization: agg[c] = dinv[c]*(sum_e ts[src] + ts[c]) + b, ts = (X@W)*dinv.

constexpr int BLK = 256;
constexpr int SH = 6;            // nodes per coarse bucket = 64
constexpr int CAP = 4096;        // slab capacity per bucket (mean ~2046, 45 sigma)
constexpr int CHUNK = 4096;      // edges per block in k_bin
constexpr int BMAX = 1024;       // max coarse buckets (N <= 65536)
constexpr int EPB = CHUNK / 256; // 16 register-cached edges per thread in k_bin
constexpr int EPT = 10;          // register-cached edges per thread in k_fine

typedef float vf4 __attribute__((ext_vector_type(4)));   // for nontemporal stores

__device__ __forceinline__ void fma4(float4& a, float s, const float4& w) {
    a.x = fmaf(s, w.x, a.x);
    a.y = fmaf(s, w.y, a.y);
    a.z = fmaf(s, w.z, a.z);
    a.w = fmaf(s, w.w, a.w);
}

__device__ __forceinline__ unsigned short f2bf(float f) {  // RNE
    unsigned u = __float_as_uint(f);
    return (unsigned short)((u + 0x7fffu + ((u >> 16) & 1u)) >> 16);
}

__device__ __forceinline__ void acc_bf8(float* a, uint4 v) {
    a[0] += __uint_as_float(v.x << 16);
    a[1] += __uint_as_float(v.x & 0xffff0000u);
    a[2] += __uint_as_float(v.y << 16);
    a[3] += __uint_as_float(v.y & 0xffff0000u);
    a[4] += __uint_as_float(v.z << 16);
    a[5] += __uint_as_float(v.z & 0xffff0000u);
    a[6] += __uint_as_float(v.w << 16);
    a[7] += __uint_as_float(v.w & 0xffff0000u);
}

// Single-pass binning: edges register-cached as col16<<16|row16 on the ONLY global
// read; LDS hist -> reserve slab slice -> emit from registers. Bucket = packed>>22.
__global__ __launch_bounds__(256) void k_bin(const int* __restrict__ row,
                                             const int* __restrict__ col,
                                             int* __restrict__ ccur,
                                             unsigned* __restrict__ binned,
                                             int E, int B) {
    __shared__ int h[BMAX];
    const int tid = threadIdx.x;
    for (int i = tid; i < B; i += 256) h[i] = 0;
    __syncthreads();
    const int e0 = blockIdx.x * CHUNK;
    unsigned ebuf[EPB];
    #pragma unroll
    for (int j = 0; j < EPB; ++j) {
        int e = e0 + tid + j * 256;
        ebuf[j] = (e < E) ? (((unsigned)col[e] << 16) | (unsigned)row[e]) : 0xFFFFFFFFu;
    }
    #pragma unroll
    for (int j = 0; j < EPB; ++j)
        if (ebuf[j] != 0xFFFFFFFFu) atomicAdd(&h[ebuf[j] >> 22], 1);
    __syncthreads();
    for (int i = tid; i < B; i += 256) {
        int c = h[i];
        if (c) h[i] = atomicAdd(&ccur[i], c);   // in-bucket base for this block
    }
    __syncthreads();
    #pragma unroll
    for (int j = 0; j < EPB; ++j) {
        unsigned e = ebuf[j];
        if (e != 0xFFFFFFFFu) {
            int b = e >> 22;
            int pos = atomicAdd(&h[b], 1);
            if (pos < CAP) binned[(size_t)b * CAP + pos] = e;
        }
    }
}

// One block per bucket: register-cached entries; fine histogram -> dinv + (start,end)
// ranges; dense ushort srcidx emit into the bucket's fixed-cap slab.
__global__ __launch_bounds__(256) void k_fine(const unsigned* __restrict__ binned,
                                              const int* __restrict__ ccur,
                                              unsigned short* __restrict__ srcidx,
                                              int2* __restrict__ range2,
                                              float* __restrict__ dinv, int N) {
    __shared__ int fine[64];
    const int b = blockIdx.x;
    const int n0 = b << SH;
    const int ebase = b * CAP;
    int ecnt = min(ccur[b], CAP);
    const int tid = threadIdx.x;
    if (tid < 64) fine[tid] = 0;
    __syncthreads();
    unsigned ebuf[EPT];
    #pragma unroll
    for (int j = 0; j < EPT; ++j) {
        int i = tid + j * 256;
        ebuf[j] = (i < ecnt) ? binned[ebase + i] : 0xFFFFFFFFu;
    }
    #pragma unroll
    for (int j = 0; j < EPT; ++j)
        if (ebuf[j] != 0xFFFFFFFFu) atomicAdd(&fine[(ebuf[j] >> 16) & 63], 1);
    for (int i = EPT * 256 + tid; i < ecnt; i += 256)   // overflow tail (normally empty)
        atomicAdd(&fine[(binned[ebase + i] >> 16) & 63], 1);
    __syncthreads();
    if (tid < 64) {
        int v = fine[tid], s = v;
        #pragma unroll
        for (int off = 1; off < 64; off <<= 1) {
            int u = __shfl_up(s, off, 64);
            if (tid >= off) s += u;
        }
        int base = ebase + s - v;
        int n = n0 + tid;
        if (n < N) {
            range2[n] = make_int2(base, base + v);
            dinv[n] = rsqrtf((float)v + 1.0f);
        }
        fine[tid] = base;
    }
    __syncthreads();
    #pragma unroll
    for (int j = 0; j < EPT; ++j) {
        unsigned e = ebuf[j];
        if (e != 0xFFFFFFFFu) {
            int pos = atomicAdd(&fine[(e >> 16) & 63], 1);
            srcidx[pos] = (unsigned short)(e & 0xFFFFu);
        }
    }
    for (int i = EPT * 256 + tid; i < ecnt; i += 256) {
        unsigned e = binned[ebase + i];
        int pos = atomicAdd(&fine[(e >> 16) & 63], 1);
        srcidx[pos] = (unsigned short)(e & 0xFFFFu);
    }
}

// T[N,64](bf16) = (op(X[N,K]) @ W) * dinv[n].  4 nodes/thread to amortize LDS W-reads.
template <int K, bool RELU, bool TWO_W>
__global__ __launch_bounds__(256) void k_gemm(const float* __restrict__ X,
                                              const float* __restrict__ Wa,
                                              const float* __restrict__ Wb,
                                              const float* __restrict__ dinv,
                                              unsigned short* __restrict__ T, int N) {
    __shared__ float4 Wl[K * 16];
    const int tid = threadIdx.x;
    for (int i = tid; i < K * 16; i += 256) {
        if (TWO_W) {
            int k = i >> 4, fgi = i & 15;
            const float* s = (fgi < 8) ? (Wa + k * 32 + fgi * 4)
                                       : (Wb + k * 32 + (fgi - 8) * 4);
            Wl[i] = *reinterpret_cast<const float4*>(s);
        } else {
            Wl[i] = reinterpret_cast<const float4*>(Wa)[i];
        }
    }
    __syncthreads();

    const int fg = tid & 15;
    const int ns = tid >> 4;
    const int nb = blockIdx.x * 64;
    const float4* Xv = reinterpret_cast<const float4*>(X);
    const float4 z = make_float4(0.f, 0.f, 0.f, 0.f);
    float4 acc[4] = {z, z, z, z};
    int n[4];
    bool v[4];
    #pragma unroll
    for (int i = 0; i < 4; ++i) { n[i] = nb + ns + i * 16; v[i] = n[i] < N; }

    for (int k4 = 0; k4 < K / 4; ++k4) {
        float4 xv[4];
        #pragma unroll
        for (int i = 0; i < 4; ++i) {
            xv[i] = v[i] ? Xv[(size_t)n[i] * (K / 4) + k4] : z;
            if (RELU) {
                xv[i].x = fmaxf(xv[i].x, 0.f); xv[i].y = fmaxf(xv[i].y, 0.f);
                xv[i].z = fmaxf(xv[i].z, 0.f); xv[i].w = fmaxf(xv[i].w, 0.f);
            }
        }
        float4 w0 = Wl[(k4 * 4 + 0) * 16 + fg];
        float4 w1 = Wl[(k4 * 4 + 1) * 16 + fg];
        float4 w2 = Wl[(k4 * 4 + 2) * 16 + fg];
        float4 w3 = Wl[(k4 * 4 + 3) * 16 + fg];
        #pragma unroll
        for (int i = 0; i < 4; ++i) {
            fma4(acc[i], xv[i].x, w0); fma4(acc[i], xv[i].y, w1);
            fma4(acc[i], xv[i].z, w2); fma4(acc[i], xv[i].w, w3);
        }
    }
    #pragma unroll
    for (int i = 0; i < 4; ++i) {
        if (v[i]) {
            float d = dinv[n[i]];
            ushort4 o;
            o.x = f2bf(acc[i].x * d); o.y = f2bf(acc[i].y * d);
            o.z = f2bf(acc[i].z * d); o.w = f2bf(acc[i].w * d);
            reinterpret_cast<ushort4*>(T)[(size_t)n[i] * 16 + fg] = o;
        }
    }
}

// out[n] = dinv[n]*(sum_{k in range(n)} Ts[srcidx[k]] + Ts[n]) + bias
// 8 threads/node, 16 B (8 bf16 feats) each, fp32 accumulate; ushort4 srcidx loads,
// 8-edge unroll for MLP. SPLIT routes feats 0:32 -> out (mu), 32:64 -> out+32N.
template <bool SPLIT>
__global__ __launch_bounds__(256) void k_gather(const int2* __restrict__ range2,
                                                const unsigned short* __restrict__ srcidx,
                                                const uint4* __restrict__ Ts,
                                                const float* __restrict__ dinv,
                                                const float* __restrict__ ba,
                                                const float* __restrict__ bb,
                                                float* __restrict__ out, int N) {
    int g = blockIdx.x * BLK + threadIdx.x;
    int n = g >> 3, fg = g & 7;
    if (n >= N) return;
    int2 rg = range2[n];
    int k = rg.x, end = rg.y;
    float a[8];
    {
        uint4 s = Ts[(size_t)n * 8 + fg];   // self loop
        a[0] = __uint_as_float(s.x << 16);
        a[1] = __uint_as_float(s.x & 0xffff0000u);
        a[2] = __uint_as_float(s.y << 16);
        a[3] = __uint_as_float(s.y & 0xffff0000u);
        a[4] = __uint_as_float(s.z << 16);
        a[5] = __uint_as_float(s.z & 0xffff0000u);
        a[6] = __uint_as_float(s.w << 16);
        a[7] = __uint_as_float(s.w & 0xffff0000u);
    }
    for (; k < end && (k & 3); ++k)          // align to ushort4
        acc_bf8(a, Ts[(size_t)srcidx[k] * 8 + fg]);
    for (; k + 8 <= end; k += 8) {
        ushort4 r0 = *reinterpret_cast<const ushort4*>(srcidx + k);
        ushort4 r1 = *reinterpret_cast<const ushort4*>(srcidx + k + 4);
        uint4 v0 = Ts[(size_t)r0.x * 8 + fg];
        uint4 v1 = Ts[(size_t)r0.y * 8 + fg];
        uint4 v2 = Ts[(size_t)r0.z * 8 + fg];
        uint4 v3 = Ts[(size_t)r0.w * 8 + fg];
        uint4 v4 = Ts[(size_t)r1.x * 8 + fg];
        uint4 v5 = Ts[(size_t)r1.y * 8 + fg];
        uint4 v6 = Ts[(size_t)r1.z * 8 + fg];
        uint4 v7 = Ts[(size_t)r1.w * 8 + fg];
        acc_bf8(a, v0); acc_bf8(a, v1); acc_bf8(a, v2); acc_bf8(a, v3);
        acc_bf8(a, v4); acc_bf8(a, v5); acc_bf8(a, v6); acc_bf8(a, v7);
    }
    if (k + 4 <= end) {
        ushort4 r0 = *reinterpret_cast<const ushort4*>(srcidx + k);
        uint4 v0 = Ts[(size_t)r0.x * 8 + fg];
        uint4 v1 = Ts[(size_t)r0.y * 8 + fg];
        uint4 v2 = Ts[(size_t)r0.z * 8 + fg];
        uint4 v3 = Ts[(size_t)r0.w * 8 + fg];
        acc_bf8(a, v0); acc_bf8(a, v1); acc_bf8(a, v2); acc_bf8(a, v3);
        k += 4;
    }
    for (; k < end; ++k)
        acc_bf8(a, Ts[(size_t)srcidx[k] * 8 + fg]);

    float d = dinv[n];
    const float* bsrc;
    float* dst;
    if (SPLIT) {
        if (fg < 4) {
            bsrc = ba + fg * 8;
            dst = out + (size_t)n * 32 + fg * 8;
        } else {
            bsrc = bb + (fg - 4) * 8;
            dst = out + (size_t)N * 32 + (size_t)n * 32 + (fg - 4) * 8;
        }
    } else {
        bsrc = ba + fg * 8;
        dst = out + (size_t)n * 64 + fg * 8;
    }
    float4 b0 = reinterpret_cast<const float4*>(bsrc)[0];
    float4 b1 = reinterpret_cast<const float4*>(bsrc)[1];
    vf4 o0, o1;
    o0.x = fmaf(a[0], d, b0.x); o0.y = fmaf(a[1], d, b0.y);
    o0.z = fmaf(a[2], d, b0.z); o0.w = fmaf(a[3], d, b0.w);
    o1.x = fmaf(a[4], d, b1.x); o1.y = fmaf(a[5], d, b1.y);
    o1.z = fmaf(a[6], d, b1.z); o1.w = fmaf(a[7], d, b1.w);
    if (SPLIT) {   // final output: write-once, bypass-cache hint
        __builtin_nontemporal_store(o0, reinterpret_cast<vf4*>(dst));
        __builtin_nontemporal_store(o1, reinterpret_cast<vf4*>(dst) + 1);
    } else {
        reinterpret_cast<vf4*>(dst)[0] = o0;
        reinterpret_cast<vf4*>(dst)[1] = o1;
    }
}

extern "C" void kernel_launch(void* const* d_in, const int* in_sizes, int n_in,
                              void* d_out, int out_size, void* d_ws, size_t ws_size,
                              hipStream_t stream) {
    const float* x   = (const float*)d_in[0];
    const int*   ei  = (const int*)d_in[1];
    const float* W1  = (const float*)d_in[2];
    const float* b1  = (const float*)d_in[3];
    const float* Wmu = (const float*)d_in[4];
    const float* bmu = (const float*)d_in[5];
    const float* Wls = (const float*)d_in[6];
    const float* bls = (const float*)d_in[7];

    const int N = in_sizes[0] / 128;
    const int E = in_sizes[1] / 2;
    const int* row = ei;            // sources
    const int* col = ei + E;        // targets
    const int B = (N + 63) >> SH;   // coarse buckets (<= BMAX)
    const size_t BCAP = (size_t)B * CAP;

    // ws layout (4B units):
    // [0,1024) ccur | [1024, 1024+BCAP) binned (t1/t2 bf16[64N]=32N ints overlay after
    // k_fine) | srcidx ushort[BCAP] (BCAP/2 ints) | dinv[N] | range2 int2[N] | agg1 f32[64N]
    int* wsi = (int*)d_ws;
    int*  ccur   = wsi;
    unsigned* binned = (unsigned*)(wsi + 1024);
    unsigned short* t1 = (unsigned short*)(wsi + 1024);   // overlays binned
    unsigned short* srcidx = (unsigned short*)(wsi + 1024 + BCAP);
    float* dinv  = (float*)(wsi + 1024 + BCAP + BCAP / 2);
    int2* range2 = (int2*)(dinv + N);
    float* agg1  = (float*)(range2 + N);
    unsigned short* t2 = t1;                              // t1 dead before gemm2 writes
    float* outp  = (float*)d_out;

    const int G = (E + CHUNK - 1) / CHUNK;

    (void)hipMemsetAsync(ccur, 0, 1024 * sizeof(int), stream);
    k_bin<<<G, 256, 0, stream>>>(row, col, ccur, binned, E, B);
    k_fine<<<B, 256, 0, stream>>>(binned, ccur, srcidx, range2, dinv, N);

    k_gemm<128, false, false><<<(N + 63) / 64, 256, 0, stream>>>(x, W1, nullptr, dinv, t1, N);
    k_gather<false><<<(N * 8 + BLK - 1) / BLK, BLK, 0, stream>>>(
        range2, srcidx, (const uint4*)t1, dinv, b1, nullptr, agg1, N);

    k_gemm<64, true, true><<<(N + 63) / 64, 256, 0, stream>>>(agg1, Wmu, Wls, dinv, t2, N);
    k_gather<true><<<(N * 8 + BLK - 1) / BLK, BLK, 0, stream>>>(
        range2, srcidx, (const uint4*)t2, dinv, bmu, bls, outp, N);
}